// Round 2
// baseline (95.539 us; speedup 1.0000x reference)
//
#include <hip/hip_runtime.h>
#include <math.h>

#define N_PTS 262144
#define WIDTH 256

// ---------------- Kernel A: streaming GEMV  y = x @ W^T + b ----------------
// One thread per point; 16-column LDS chunks; SoA output yws[j][p].

__global__ __launch_bounds__(256, 8) void gemv_kernel(
    const float* __restrict__ x,
    const float* __restrict__ fw,
    const float* __restrict__ fb,
    float* __restrict__ yws)
{
    // pad to 20 floats/row: 80B row stride (16B-aligned for ds_read_b128),
    // 20t mod 32 cycles through 8 distinct bank-quads -> uniform bank load
    __shared__ float xs[256][20];
    const int t  = threadIdx.x;
    const int p0 = blockIdx.x << 8;

    float y[9];
#pragma unroll
    for (int j = 0; j < 9; ++j) y[j] = 0.f;

    for (int kc = 0; kc < 16; ++kc) {
        const int k0 = kc << 4;
        // stage 256 pts x 16 cols, coalesced float4 (4 per row)
#pragma unroll
        for (int i = 0; i < 4; ++i) {
            const int flat = (i << 8) + t;      // float4 index 0..1023
            const int row  = flat >> 2;
            const int c4   = flat & 3;
            const float4 v = *reinterpret_cast<const float4*>(
                x + (size_t)(p0 + row) * WIDTH + k0 + (c4 << 2));
            *reinterpret_cast<float4*>(&xs[row][c4 << 2]) = v;
        }
        __syncthreads();
#pragma unroll
        for (int q = 0; q < 4; ++q) {
            const float4 xv = *reinterpret_cast<const float4*>(&xs[t][q << 2]);
            const float xa[4] = {xv.x, xv.y, xv.z, xv.w};
#pragma unroll
            for (int c = 0; c < 4; ++c) {
                const int k = k0 + (q << 2) + c;   // uniform -> scalar loads
#pragma unroll
                for (int j = 0; j < 9; ++j)
                    y[j] = fmaf(xa[c], fw[j * WIDTH + k], y[j]);
            }
        }
        __syncthreads();
    }

    const int p = p0 + t;
#pragma unroll
    for (int j = 0; j < 9; ++j)
        yws[(size_t)j * N_PTS + p] = y[j] + fb[j];   // SoA, coalesced
}

// ---------------- Kernel B: fp64 special-Procrustes epilogue ----------------

__device__ __forceinline__ void jrot(double &app, double &aqq, double &apq,
                                     double &arp, double &arq,
                                     double &vp0, double &vq0,
                                     double &vp1, double &vq1,
                                     double &vp2, double &vq2)
{
    double a = apq;
    if (fabs(a) < 1e-300) return;
    double theta = (aqq - app) / (2.0 * a);
    double tt = copysign(1.0, theta) / (fabs(theta) + sqrt(1.0 + theta * theta));
    double c = 1.0 / sqrt(1.0 + tt * tt);
    double s = tt * c;
    app -= tt * a;
    aqq += tt * a;
    apq = 0.0;
    double rp = arp, rq = arq;
    arp = c * rp - s * rq;
    arq = s * rp + c * rq;
    double t0p = vp0, t0q = vq0; vp0 = c * t0p - s * t0q; vq0 = s * t0p + c * t0q;
    double t1p = vp1, t1q = vq1; vp1 = c * t1p - s * t1q; vq1 = s * t1p + c * t1q;
    double t2p = vp2, t2q = vq2; vp2 = c * t2p - s * t2q; vq2 = s * t2p + c * t2q;
}

__global__ __launch_bounds__(256) void svd_kernel(
    const float* __restrict__ yws,
    float* __restrict__ out)
{
    const int p = (blockIdx.x << 8) + threadIdx.x;

    float y[9];
#pragma unroll
    for (int j = 0; j < 9; ++j)
        y[j] = yws[(size_t)j * N_PTS + p];          // SoA, coalesced

    const double m00 = y[0], m01 = y[1], m02 = y[2];
    const double m10 = y[3], m11 = y[4], m12 = y[5];
    const double m20 = y[6], m21 = y[7], m22 = y[8];

    double a00 = m00*m00 + m10*m10 + m20*m20;
    double a01 = m00*m01 + m10*m11 + m20*m21;
    double a02 = m00*m02 + m10*m12 + m20*m22;
    double a11 = m01*m01 + m11*m11 + m21*m21;
    double a12 = m01*m02 + m11*m12 + m21*m22;
    double a22 = m02*m02 + m12*m12 + m22*m22;

    double v[3][3] = { {1,0,0}, {0,1,0}, {0,0,1} };

#pragma unroll
    for (int sw = 0; sw < 4; ++sw) {
        jrot(a00, a11, a01, a02, a12,
             v[0][0], v[0][1], v[1][0], v[1][1], v[2][0], v[2][1]);
        jrot(a00, a22, a02, a01, a12,
             v[0][0], v[0][2], v[1][0], v[1][2], v[2][0], v[2][2]);
        jrot(a11, a22, a12, a01, a02,
             v[0][1], v[0][2], v[1][1], v[1][2], v[2][1], v[2][2]);
    }

    double d0 = a00, d1 = a11, d2 = a22, tmp;
    if (d0 < d1) { tmp=d0; d0=d1; d1=tmp;
        tmp=v[0][0]; v[0][0]=v[0][1]; v[0][1]=tmp;
        tmp=v[1][0]; v[1][0]=v[1][1]; v[1][1]=tmp;
        tmp=v[2][0]; v[2][0]=v[2][1]; v[2][1]=tmp; }
    if (d0 < d2) { tmp=d0; d0=d2; d2=tmp;
        tmp=v[0][0]; v[0][0]=v[0][2]; v[0][2]=tmp;
        tmp=v[1][0]; v[1][0]=v[1][2]; v[1][2]=tmp;
        tmp=v[2][0]; v[2][0]=v[2][2]; v[2][2]=tmp; }
    if (d1 < d2) { tmp=d1; d1=d2; d2=tmp;
        tmp=v[0][1]; v[0][1]=v[0][2]; v[0][2]=tmp;
        tmp=v[1][1]; v[1][1]=v[1][2]; v[1][2]=tmp;
        tmp=v[2][1]; v[2][1]=v[2][2]; v[2][2]=tmp; }

    const double v1x = v[0][0], v1y = v[1][0], v1z = v[2][0];
    const double v2x = v[0][1], v2y = v[1][1], v2z = v[2][1];

    double u1x = m00*v1x + m01*v1y + m02*v1z;
    double u1y = m10*v1x + m11*v1y + m12*v1z;
    double u1z = m20*v1x + m21*v1y + m22*v1z;
    double inv1 = 1.0 / (sqrt(u1x*u1x + u1y*u1y + u1z*u1z) + 1e-300);
    u1x *= inv1; u1y *= inv1; u1z *= inv1;

    double u2x = m00*v2x + m01*v2y + m02*v2z;
    double u2y = m10*v2x + m11*v2y + m12*v2z;
    double u2z = m20*v2x + m21*v2y + m22*v2z;
    const double d12 = u1x*u2x + u1y*u2y + u1z*u2z;
    u2x -= d12*u1x; u2y -= d12*u1y; u2z -= d12*u1z;
    double inv2 = 1.0 / (sqrt(u2x*u2x + u2y*u2y + u2z*u2z) + 1e-300);
    u2x *= inv2; u2y *= inv2; u2z *= inv2;

    const double u3x = u1y*u2z - u1z*u2y;
    const double u3y = u1z*u2x - u1x*u2z;
    const double u3z = u1x*u2y - u1y*u2x;
    const double v3x = v1y*v2z - v1z*v2y;
    const double v3y = v1z*v2x - v1x*v2z;
    const double v3z = v1x*v2y - v1y*v2x;

    float r[9];
    r[0] = (float)(u1x*v1x + u2x*v2x + u3x*v3x);
    r[1] = (float)(u1x*v1y + u2x*v2y + u3x*v3y);
    r[2] = (float)(u1x*v1z + u2x*v2z + u3x*v3z);
    r[3] = (float)(u1y*v1x + u2y*v2x + u3y*v3x);
    r[4] = (float)(u1y*v1y + u2y*v2y + u3y*v3y);
    r[5] = (float)(u1y*v1z + u2y*v2z + u3y*v3z);
    r[6] = (float)(u1z*v1x + u2z*v2x + u3z*v3x);
    r[7] = (float)(u1z*v1y + u2z*v2y + u3z*v3y);
    r[8] = (float)(u1z*v1z + u2z*v2z + u3z*v3z);

    float* o = out + (size_t)p * 9;
#pragma unroll
    for (int j = 0; j < 9; ++j) o[j] = r[j];
}

extern "C" void kernel_launch(void* const* d_in, const int* in_sizes, int n_in,
                              void* d_out, int out_size, void* d_ws, size_t ws_size,
                              hipStream_t stream) {
    const float* x  = (const float*)d_in[0];
    const float* fw = (const float*)d_in[1];
    const float* fb = (const float*)d_in[2];
    float* out = (float*)d_out;
    float* yws = (float*)d_ws;           // 9 * N_PTS floats = 9.4 MB

    dim3 grid(N_PTS / 256), block(256);
    hipLaunchKernelGGL(gemv_kernel, grid, block, 0, stream, x, fw, fb, yws);
    hipLaunchKernelGGL(svd_kernel,  grid, block, 0, stream, yws, out);
}

// Round 3
// 69.528 us; speedup vs baseline: 1.3741x; 1.3741x over previous
//
#include <hip/hip_runtime.h>
#include <math.h>

#define N_PTS 262144
#define WIDTH 256

// fp32 Jacobi rotation on symmetric 3x3, updating eigenvector matrix columns
__device__ __forceinline__ void jrot(float &app, float &aqq, float &apq,
                                     float &arp, float &arq,
                                     float &vp0, float &vq0,
                                     float &vp1, float &vq1,
                                     float &vp2, float &vq2)
{
    float a = apq;
    if (fabsf(a) < 1e-20f) return;
    float theta = (aqq - app) / (2.0f * a);
    float tt = copysignf(1.0f, theta) / (fabsf(theta) + sqrtf(1.0f + theta * theta));
    float c = 1.0f / sqrtf(1.0f + tt * tt);
    float s = tt * c;
    app -= tt * a;
    aqq += tt * a;
    apq = 0.0f;
    float rp = arp, rq = arq;
    arp = c * rp - s * rq;
    arq = s * rp + c * rq;
    float t0p = vp0, t0q = vq0; vp0 = c * t0p - s * t0q; vq0 = s * t0p + c * t0q;
    float t1p = vp1, t1q = vq1; vp1 = c * t1p - s * t1q; vq1 = s * t1p + c * t1q;
    float t2p = vp2, t2q = vq2; vp2 = c * t2p - s * t2q; vq2 = s * t2p + c * t2q;
}

__global__ __launch_bounds__(256, 4) void so3_kernel(
    const float* __restrict__ x,
    const float* __restrict__ fw,
    const float* __restrict__ fb,
    float* __restrict__ out)
{
    // pad 17: odd stride -> stride-17 scalar reads hit all 32 banks (free);
    // 4-lane-group scalar writes are <=2-way (free). 17.4 KB -> LDS allows 9 blocks/CU.
    __shared__ float xs[256][17];
    const int t  = threadIdx.x;
    const int p0 = blockIdx.x << 8;

    float y[9];
#pragma unroll
    for (int j = 0; j < 9; ++j) y[j] = 0.f;

    // prologue: prefetch chunk 0 into registers
    float4 pre[4];
#pragma unroll
    for (int i = 0; i < 4; ++i) {
        const int flat = (i << 8) + t;
        const int row  = flat >> 2;
        const int c4   = flat & 3;
        pre[i] = *reinterpret_cast<const float4*>(
            x + (size_t)(p0 + row) * WIDTH + (c4 << 2));
    }

    for (int kc = 0; kc < 16; ++kc) {
        // write prefetched chunk to LDS (scalar stores, pad-17 layout)
#pragma unroll
        for (int i = 0; i < 4; ++i) {
            const int flat = (i << 8) + t;
            const int row  = flat >> 2;
            const int c    = (flat & 3) << 2;
            xs[row][c + 0] = pre[i].x;
            xs[row][c + 1] = pre[i].y;
            xs[row][c + 2] = pre[i].z;
            xs[row][c + 3] = pre[i].w;
        }
        __syncthreads();

        // issue next chunk's loads while computing this one
        if (kc < 15) {
            const int k0n = (kc + 1) << 4;
#pragma unroll
            for (int i = 0; i < 4; ++i) {
                const int flat = (i << 8) + t;
                const int row  = flat >> 2;
                const int c4   = flat & 3;
                pre[i] = *reinterpret_cast<const float4*>(
                    x + (size_t)(p0 + row) * WIDTH + k0n + (c4 << 2));
            }
        }

        const int k0 = kc << 4;
#pragma unroll
        for (int kk = 0; kk < 16; ++kk) {
            const float xv = xs[t][kk];          // stride-17 -> conflict-free
            const int k = k0 + kk;               // uniform -> scalar s_loads of fw
#pragma unroll
            for (int j = 0; j < 9; ++j)
                y[j] = fmaf(xv, fw[j * WIDTH + k], y[j]);
        }
        __syncthreads();
    }

#pragma unroll
    for (int j = 0; j < 9; ++j) y[j] += fb[j];

    // ---- fp32 3x3 special Procrustes:  R = U diag(1,1,det) V^T ----
    const float m00 = y[0], m01 = y[1], m02 = y[2];
    const float m10 = y[3], m11 = y[4], m12 = y[5];
    const float m20 = y[6], m21 = y[7], m22 = y[8];

    float a00 = m00*m00 + m10*m10 + m20*m20;
    float a01 = m00*m01 + m10*m11 + m20*m21;
    float a02 = m00*m02 + m10*m12 + m20*m22;
    float a11 = m01*m01 + m11*m11 + m21*m21;
    float a12 = m01*m02 + m11*m12 + m21*m22;
    float a22 = m02*m02 + m12*m12 + m22*m22;

    float v[3][3] = { {1,0,0}, {0,1,0}, {0,0,1} };

#pragma unroll
    for (int sw = 0; sw < 5; ++sw) {
        jrot(a00, a11, a01, a02, a12,
             v[0][0], v[0][1], v[1][0], v[1][1], v[2][0], v[2][1]);
        jrot(a00, a22, a02, a01, a12,
             v[0][0], v[0][2], v[1][0], v[1][2], v[2][0], v[2][2]);
        jrot(a11, a22, a12, a01, a02,
             v[0][1], v[0][2], v[1][1], v[1][2], v[2][1], v[2][2]);
    }

    float d0 = a00, d1 = a11, d2 = a22, tmp;
    if (d0 < d1) { tmp=d0; d0=d1; d1=tmp;
        tmp=v[0][0]; v[0][0]=v[0][1]; v[0][1]=tmp;
        tmp=v[1][0]; v[1][0]=v[1][1]; v[1][1]=tmp;
        tmp=v[2][0]; v[2][0]=v[2][1]; v[2][1]=tmp; }
    if (d0 < d2) { tmp=d0; d0=d2; d2=tmp;
        tmp=v[0][0]; v[0][0]=v[0][2]; v[0][2]=tmp;
        tmp=v[1][0]; v[1][0]=v[1][2]; v[1][2]=tmp;
        tmp=v[2][0]; v[2][0]=v[2][2]; v[2][2]=tmp; }
    if (d1 < d2) { tmp=d1; d1=d2; d2=tmp;
        tmp=v[0][1]; v[0][1]=v[0][2]; v[0][2]=tmp;
        tmp=v[1][1]; v[1][1]=v[1][2]; v[1][2]=tmp;
        tmp=v[2][1]; v[2][1]=v[2][2]; v[2][2]=tmp; }

    const float v1x = v[0][0], v1y = v[1][0], v1z = v[2][0];
    const float v2x = v[0][1], v2y = v[1][1], v2z = v[2][1];

    // u1 = normalize(M v1)
    float u1x = m00*v1x + m01*v1y + m02*v1z;
    float u1y = m10*v1x + m11*v1y + m12*v1z;
    float u1z = m20*v1x + m21*v1y + m22*v1z;
    float inv1 = 1.0f / (sqrtf(u1x*u1x + u1y*u1y + u1z*u1z) + 1e-30f);
    u1x *= inv1; u1y *= inv1; u1z *= inv1;

    // u2 = normalize(M v2 - (u1 . M v2) u1)
    float u2x = m00*v2x + m01*v2y + m02*v2z;
    float u2y = m10*v2x + m11*v2y + m12*v2z;
    float u2z = m20*v2x + m21*v2y + m22*v2z;
    const float d12 = u1x*u2x + u1y*u2y + u1z*u2z;
    u2x -= d12*u1x; u2y -= d12*u1y; u2z -= d12*u1z;
    float inv2 = 1.0f / (sqrtf(u2x*u2x + u2y*u2y + u2z*u2z) + 1e-30f);
    u2x *= inv2; u2y *= inv2; u2z *= inv2;

    // u3 = u1 x u2 ; v3 = v1 x v2
    const float u3x = u1y*u2z - u1z*u2y;
    const float u3y = u1z*u2x - u1x*u2z;
    const float u3z = u1x*u2y - u1y*u2x;
    const float v3x = v1y*v2z - v1z*v2y;
    const float v3y = v1z*v2x - v1x*v2z;
    const float v3z = v1x*v2y - v1y*v2x;

    float r[9];
    r[0] = u1x*v1x + u2x*v2x + u3x*v3x;
    r[1] = u1x*v1y + u2x*v2y + u3x*v3y;
    r[2] = u1x*v1z + u2x*v2z + u3x*v3z;
    r[3] = u1y*v1x + u2y*v2x + u3y*v3x;
    r[4] = u1y*v1y + u2y*v2y + u3y*v3y;
    r[5] = u1y*v1z + u2y*v2z + u3y*v3z;
    r[6] = u1z*v1x + u2z*v2x + u3z*v3x;
    r[7] = u1z*v1y + u2z*v2y + u3z*v3y;
    r[8] = u1z*v1z + u2z*v2z + u3z*v3z;

    float* o = out + (size_t)(p0 + t) * 9;
#pragma unroll
    for (int j = 0; j < 9; ++j) o[j] = r[j];
}

extern "C" void kernel_launch(void* const* d_in, const int* in_sizes, int n_in,
                              void* d_out, int out_size, void* d_ws, size_t ws_size,
                              hipStream_t stream) {
    const float* x  = (const float*)d_in[0];
    const float* fw = (const float*)d_in[1];
    const float* fb = (const float*)d_in[2];
    float* out = (float*)d_out;
    dim3 grid(N_PTS / 256), block(256);
    hipLaunchKernelGGL(so3_kernel, grid, block, 0, stream, x, fw, fb, out);
}

// Round 4
// 65.813 us; speedup vs baseline: 1.4517x; 1.0565x over previous
//
#include <hip/hip_runtime.h>
#include <math.h>

#define N_PTS 262144
#define WIDTH 256

// fp32 Jacobi rotation on symmetric 3x3, updating eigenvector matrix columns
__device__ __forceinline__ void jrot(float &app, float &aqq, float &apq,
                                     float &arp, float &arq,
                                     float &vp0, float &vq0,
                                     float &vp1, float &vq1,
                                     float &vp2, float &vq2)
{
    float a = apq;
    if (fabsf(a) < 1e-20f) return;
    float theta = (aqq - app) / (2.0f * a);
    float tt = copysignf(1.0f, theta) / (fabsf(theta) + sqrtf(1.0f + theta * theta));
    float c = 1.0f / sqrtf(1.0f + tt * tt);
    float s = tt * c;
    app -= tt * a;
    aqq += tt * a;
    apq = 0.0f;
    float rp = arp, rq = arq;
    arp = c * rp - s * rq;
    arq = s * rp + c * rq;
    float t0p = vp0, t0q = vq0; vp0 = c * t0p - s * t0q; vq0 = s * t0p + c * t0q;
    float t1p = vp1, t1q = vq1; vp1 = c * t1p - s * t1q; vq1 = s * t1p + c * t1q;
    float t2p = vp2, t2q = vq2; vp2 = c * t2p - s * t2q; vq2 = s * t2p + c * t2q;
}

__global__ __launch_bounds__(256, 4) void so3_kernel(
    const float* __restrict__ x,
    const float* __restrict__ fw,
    const float* __restrict__ fb,
    float* __restrict__ out)
{
    // [256][33]: scalar reads xs[t][kk] -> bank (t+kk)%32, conflict-free;
    // staging scalar writes are <=2-way (free). 33.8 KB -> 4 blocks/CU.
    __shared__ float xs[256][33];
    const int t  = threadIdx.x;
    const int p0 = blockIdx.x << 8;

    float y[9];
#pragma unroll
    for (int j = 0; j < 9; ++j) y[j] = 0.f;

    // prologue: prefetch chunk 0 (32 cols = one full 128B L2 line per row)
    float4 pre[8];
#pragma unroll
    for (int i = 0; i < 8; ++i) {
        const int flat = (i << 8) + t;       // float4 idx 0..2047
        const int row  = flat >> 3;          // 8 float4 per row
        const int c4   = flat & 7;
        pre[i] = *reinterpret_cast<const float4*>(
            x + (size_t)(p0 + row) * WIDTH + (c4 << 2));
    }

    for (int kc = 0; kc < 8; ++kc) {
        // write prefetched chunk to LDS
#pragma unroll
        for (int i = 0; i < 8; ++i) {
            const int flat = (i << 8) + t;
            const int row  = flat >> 3;
            const int c    = (flat & 7) << 2;
            xs[row][c + 0] = pre[i].x;
            xs[row][c + 1] = pre[i].y;
            xs[row][c + 2] = pre[i].z;
            xs[row][c + 3] = pre[i].w;
        }
        __syncthreads();

        // issue next chunk's global loads; they fly over this chunk's compute
        if (kc < 7) {
            const int k0n = (kc + 1) << 5;
#pragma unroll
            for (int i = 0; i < 8; ++i) {
                const int flat = (i << 8) + t;
                const int row  = flat >> 3;
                const int c4   = flat & 7;
                pre[i] = *reinterpret_cast<const float4*>(
                    x + (size_t)(p0 + row) * WIDTH + k0n + (c4 << 2));
            }
        }

        const int k0 = kc << 5;
#pragma unroll
        for (int kk = 0; kk < 32; ++kk) {
            const float xv = xs[t][kk];          // bank (t+kk)%32: conflict-free
            const int k = k0 + kk;               // uniform -> scalar s_loads of fw
#pragma unroll
            for (int j = 0; j < 9; ++j)
                y[j] = fmaf(xv, fw[j * WIDTH + k], y[j]);
        }
        __syncthreads();
    }

#pragma unroll
    for (int j = 0; j < 9; ++j) y[j] += fb[j];

    // ---- fp32 3x3 special Procrustes:  R = U diag(1,1,det) V^T ----
    const float m00 = y[0], m01 = y[1], m02 = y[2];
    const float m10 = y[3], m11 = y[4], m12 = y[5];
    const float m20 = y[6], m21 = y[7], m22 = y[8];

    float a00 = m00*m00 + m10*m10 + m20*m20;
    float a01 = m00*m01 + m10*m11 + m20*m21;
    float a02 = m00*m02 + m10*m12 + m20*m22;
    float a11 = m01*m01 + m11*m11 + m21*m21;
    float a12 = m01*m02 + m11*m12 + m21*m22;
    float a22 = m02*m02 + m12*m12 + m22*m22;

    float v[3][3] = { {1,0,0}, {0,1,0}, {0,0,1} };

#pragma unroll
    for (int sw = 0; sw < 5; ++sw) {
        jrot(a00, a11, a01, a02, a12,
             v[0][0], v[0][1], v[1][0], v[1][1], v[2][0], v[2][1]);
        jrot(a00, a22, a02, a01, a12,
             v[0][0], v[0][2], v[1][0], v[1][2], v[2][0], v[2][2]);
        jrot(a11, a22, a12, a01, a02,
             v[0][1], v[0][2], v[1][1], v[1][2], v[2][1], v[2][2]);
    }

    float d0 = a00, d1 = a11, d2 = a22, tmp;
    if (d0 < d1) { tmp=d0; d0=d1; d1=tmp;
        tmp=v[0][0]; v[0][0]=v[0][1]; v[0][1]=tmp;
        tmp=v[1][0]; v[1][0]=v[1][1]; v[1][1]=tmp;
        tmp=v[2][0]; v[2][0]=v[2][1]; v[2][1]=tmp; }
    if (d0 < d2) { tmp=d0; d0=d2; d2=tmp;
        tmp=v[0][0]; v[0][0]=v[0][2]; v[0][2]=tmp;
        tmp=v[1][0]; v[1][0]=v[1][2]; v[1][2]=tmp;
        tmp=v[2][0]; v[2][0]=v[2][2]; v[2][2]=tmp; }
    if (d1 < d2) { tmp=d1; d1=d2; d2=tmp;
        tmp=v[0][1]; v[0][1]=v[0][2]; v[0][2]=tmp;
        tmp=v[1][1]; v[1][1]=v[1][2]; v[1][2]=tmp;
        tmp=v[2][1]; v[2][1]=v[2][2]; v[2][2]=tmp; }

    const float v1x = v[0][0], v1y = v[1][0], v1z = v[2][0];
    const float v2x = v[0][1], v2y = v[1][1], v2z = v[2][1];

    // u1 = normalize(M v1)
    float u1x = m00*v1x + m01*v1y + m02*v1z;
    float u1y = m10*v1x + m11*v1y + m12*v1z;
    float u1z = m20*v1x + m21*v1y + m22*v1z;
    float inv1 = 1.0f / (sqrtf(u1x*u1x + u1y*u1y + u1z*u1z) + 1e-30f);
    u1x *= inv1; u1y *= inv1; u1z *= inv1;

    // u2 = normalize(M v2 - (u1 . M v2) u1)
    float u2x = m00*v2x + m01*v2y + m02*v2z;
    float u2y = m10*v2x + m11*v2y + m12*v2z;
    float u2z = m20*v2x + m21*v2y + m22*v2z;
    const float d12 = u1x*u2x + u1y*u2y + u1z*u2z;
    u2x -= d12*u1x; u2y -= d12*u1y; u2z -= d12*u1z;
    float inv2 = 1.0f / (sqrtf(u2x*u2x + u2y*u2y + u2z*u2z) + 1e-30f);
    u2x *= inv2; u2y *= inv2; u2z *= inv2;

    // u3 = u1 x u2 ; v3 = v1 x v2
    const float u3x = u1y*u2z - u1z*u2y;
    const float u3y = u1z*u2x - u1x*u2z;
    const float u3z = u1x*u2y - u1y*u2x;
    const float v3x = v1y*v2z - v1z*v2y;
    const float v3y = v1z*v2x - v1x*v2z;
    const float v3z = v1x*v2y - v1y*v2x;

    float r[9];
    r[0] = u1x*v1x + u2x*v2x + u3x*v3x;
    r[1] = u1x*v1y + u2x*v2y + u3x*v3y;
    r[2] = u1x*v1z + u2x*v2z + u3x*v3z;
    r[3] = u1y*v1x + u2y*v2x + u3y*v3x;
    r[4] = u1y*v1y + u2y*v2y + u3y*v3y;
    r[5] = u1y*v1z + u2y*v2z + u3y*v3z;
    r[6] = u1z*v1x + u2z*v2x + u3z*v3x;
    r[7] = u1z*v1y + u2z*v2y + u3z*v3y;
    r[8] = u1z*v1z + u2z*v2z + u3z*v3z;

    float* o = out + (size_t)(p0 + t) * 9;
#pragma unroll
    for (int j = 0; j < 9; ++j) o[j] = r[j];
}

extern "C" void kernel_launch(void* const* d_in, const int* in_sizes, int n_in,
                              void* d_out, int out_size, void* d_ws, size_t ws_size,
                              hipStream_t stream) {
    const float* x  = (const float*)d_in[0];
    const float* fw = (const float*)d_in[1];
    const float* fb = (const float*)d_in[2];
    float* out = (float*)d_out;
    dim3 grid(N_PTS / 256), block(256);
    hipLaunchKernelGGL(so3_kernel, grid, block, 0, stream, x, fw, fb, out);
}